// Round 6
// baseline (362.085 us; speedup 1.0000x reference)
//
#include <hip/hip_runtime.h>

typedef unsigned short u16;
typedef __bf16 bf16x8 __attribute__((ext_vector_type(8)));
typedef float f32x4 __attribute__((ext_vector_type(4)));
typedef unsigned int u32x4 __attribute__((ext_vector_type(4)));

#define AS1 __attribute__((address_space(1)))
#define AS3 __attribute__((address_space(3)))

__device__ inline u16 f2bf(float f) {
    union { float f; unsigned u; } c; c.f = f;
    unsigned u = c.u;
    u += 0x7fffu + ((u >> 16) & 1u);   // round-to-nearest-even
    return (u16)(u >> 16);
}
__device__ inline float bf2f(u16 b) {
    union { unsigned u; float f; } c; c.u = ((unsigned)b) << 16;
    return c.f;
}

__device__ inline void async_cp16(const void* g, void* l) {
    __builtin_amdgcn_global_load_lds((const AS1 void*)g, (AS3 void*)l, 16, 0, 0);
}

// ---------------------------------------------------------------------------
// Fused input conversions in ONE launch:
//   blocks [0, 8192):      x fp32 -> bf16, 8 elems/thread (16777216 elems)
//   blocks [8192, 18432):  wq|wk|wv -> wqkv, wo -> wo_bf, 4 elems/thread
// ---------------------------------------------------------------------------
__global__ __launch_bounds__(256)
void conv_all(const float* __restrict__ x,
              const float* __restrict__ wq, const float* __restrict__ wk,
              const float* __restrict__ wv, const float* __restrict__ wo,
              u16* __restrict__ x_bf, u16* __restrict__ wqkv,
              u16* __restrict__ wo_bf) {
    int b = blockIdx.x;
    if (b < 8192) {
        int i = (b * 256 + threadIdx.x) * 8;
        float4 f0 = *(const float4*)(x + i);
        float4 f1 = *(const float4*)(x + i + 4);
        union { u16 h[8]; uint4 v; } o;
        o.h[0] = f2bf(f0.x); o.h[1] = f2bf(f0.y);
        o.h[2] = f2bf(f0.z); o.h[3] = f2bf(f0.w);
        o.h[4] = f2bf(f1.x); o.h[5] = f2bf(f1.y);
        o.h[6] = f2bf(f1.z); o.h[7] = f2bf(f1.w);
        *(uint4*)(x_bf + i) = o.v;
    } else {
        int i = ((b - 8192) * 256 + threadIdx.x) * 4;
        const float* src;
        u16* dst;
        if (i < 4194304)       { src = wq + i;           dst = wqkv + i; }
        else if (i < 5242880)  { src = wk + (i-4194304); dst = wqkv + i; }
        else if (i < 6291456)  { src = wv + (i-5242880); dst = wqkv + i; }
        else                   { src = wo + (i-6291456); dst = wo_bf + (i-6291456); }
        float4 f = *(const float4*)src;
        union { u16 h[4]; uint2 v; } o;
        o.h[0] = f2bf(f.x); o.h[1] = f2bf(f.y);
        o.h[2] = f2bf(f.z); o.h[3] = f2bf(f.w);
        *(uint2*)dst = o.v;
    }
}

// ---------------------------------------------------------------------------
// REG-STAGED variant (QKV): 256 x (NI*64) x (BK=64), C = A * B^T.
// NO LDS-DMA anywhere (round-4 failure root cause: manual vmcnt over a MIXED
// queue of global_load_lds + global_load assumed cross-type in-order
// completion; LDS-DMA is not ordered vs VGPR loads).
//   A: global -> VGPR (areg, P1) -> ds_write_b128 into swizzled LDS (P4).
//      The areg->ds_write dep is a REGISTER dep: compiler auto-inserts the
//      counted vmcnt (leaves bg loads in flight). No manual vmcnt at all.
//   B: global -> VGPR fragments directly (bgA/bgB double buffer, 1-tile
//      lookahead). Same bytes as the old LDS path: col = col0+wn*NI*16+lm,
//      k = kb + quad*8 + s*32  (swizzle identity: LDS[r][p]=glob[r][p^(r&7)],
//      read p = (4s+quad)^(r&7) => glob[r][4s+quad]).
// LDS traffic/tile/CU: 233 KiB -> 160 KiB (below the 1862-cyc MFMA floor).
//
// Correctness invariants (compiler-independent):
//   - WLG(0)@P4 drains ALL ds_reads and the 4 ds_writes before the tile-end
//     BAR: reads-drained (region reusable) + writes-published (next P1 reads).
//   - ds_writes at P4 target buffer (u+1)&1, whose last readers (tile u-1
//     F/G) drained at P4(u-1)'s WLG(0), one full tile earlier.
//   - lgkm queue is LDS-ops-only at every counted WLG (in-order); all
//     register deps (bg vmcnt, areg vmcnt, ds_read lgkm) are additionally
//     compiler-enforced -- the counted WLG(4)s are performance hints only.
// Requires: M %256==0, N %(NI*64)==0, K %128==0.
// ---------------------------------------------------------------------------
template <int NI, bool BF16_OUT>
__global__ __launch_bounds__(512, 2)
void gemm_breg(const u16* __restrict__ A, const u16* __restrict__ B,
               void* __restrict__ Cout, int N, int K) {
    __shared__ __align__(16) char ldsc[65536];   // A only: 2 bufs x 32 KiB

    const int tid  = threadIdx.x;
    const int w    = tid >> 6;
    const int lane = tid & 63;
    const int row0 = blockIdx.x * 256;
    const int col0 = blockIdx.y * (NI * 64);
    const int wm = w >> 2, wn = w & 3;
    const int lm = lane & 15, quad = lane >> 4;

    const int NT  = K / 64;     // K-tiles
    const int NIT = K / 128;    // main-loop iterations (2 tiles each)
    const int K64 = K * 64;

    // A staging: lane l covers row (8w + (l>>3)) within a 64-row unit,
    // LDS chunk position l&7 holds global chunk (l&7)^(l>>3)  (swizzle)
    const int sr  = lane >> 3;
    const int stC = ((lane & 7) ^ sr) * 8;
    const u16* pA = A + (size_t)(row0 + w * 8 + sr) * K + stC;
    const int wrOff = w * 1024 + lane * 16;   // + unit*8192 + buf byte-base

    // A fragment read bases (byte offsets)
    const int cx0   = (quad ^ (lm & 7)) * 16;
    const int cx1   = cx0 ^ 64;
    const int aBase = (wm * 128 + lm) * 128;

    // B per-lane base (direct global)
    const u16* pB = B + (size_t)(col0 + wn * (NI * 16) + lm) * K + quad * 8;

    f32x4 acc[8][NI];
#pragma unroll
    for (int i = 0; i < 8; i++)
#pragma unroll
        for (int j = 0; j < NI; j++) acc[i][j] = (f32x4){0.f, 0.f, 0.f, 0.f};

#define LDRB(off) (*(const bf16x8*)(ldsc + (off)))
#define SBq __builtin_amdgcn_sched_barrier(0)
#define BARq __builtin_amdgcn_s_barrier()
#define WLGq(n) asm volatile("s_waitcnt lgkmcnt(" #n ")" ::: "memory")

#define LD_AREG(V)                                                            \
    {                                                                         \
        int kb_ = ((V) < NT ? (V) : NT - 1) * 64;  /* tail: dup, unused */    \
        _Pragma("unroll")                                                     \
        for (int uu = 0; uu < 4; uu++)                                        \
            areg[uu] = *(const AS1 u32x4*)(pA + (size_t)uu * K64 + kb_);      \
    }
#define WR_AREG(BUF)                                                          \
    _Pragma("unroll")                                                         \
    for (int uu = 0; uu < 4; uu++)                                            \
        *(u32x4*)(ldsc + (BUF) + uu * 8192 + wrOff) = areg[uu];
#define RD_A2(DST, BASEOFF, MIBASE)                                           \
    _Pragma("unroll")                                                         \
    for (int j = 0; j < 2; j++) {                                             \
        DST[j][0] = LDRB((BASEOFF) + aBase + ((MIBASE) + j) * 2048 + cx0);    \
        DST[j][1] = LDRB((BASEOFF) + aBase + ((MIBASE) + j) * 2048 + cx1);    \
    }
#define LD_BG(DST, V)                                                         \
    {                                                                         \
        int kb_ = ((V) < NT ? (V) : NT - 1) * 64;                             \
        _Pragma("unroll")                                                     \
        for (int ni = 0; ni < NI; ni++) {                                     \
            DST[ni][0] = *(const AS1 bf16x8*)(pB + (size_t)ni * 16 * K + kb_);\
            DST[ni][1] = *(const AS1 bf16x8*)(pB + (size_t)ni * 16 * K + kb_ + 32);\
        }                                                                     \
    }
#define MFMA_T(MI0, AF, BG)                                                   \
    __builtin_amdgcn_s_setprio(1);                                            \
    _Pragma("unroll")                                                         \
    for (int s = 0; s < 2; s++)                                               \
        _Pragma("unroll")                                                     \
        for (int j = 0; j < 2; j++)                                           \
            _Pragma("unroll")                                                 \
            for (int ni = 0; ni < NI; ni++)                                   \
                acc[(MI0) + j][ni] = __builtin_amdgcn_mfma_f32_16x16x32_bf16( \
                    AF[j][s], BG[ni][s], acc[(MI0) + j][ni], 0, 0, 0);        \
    __builtin_amdgcn_s_setprio(0);

    bf16x8 bgA[NI][2], bgB[NI][2], F[2][2], G[2][2];
    u32x4 areg[4];

    // prologue: areg(0) -> LDS buf0; bg(0) stays in flight (compiler inserts
    // the counted vmcnt before the first ds_write / first MFMA use).
    LD_AREG(0)
    SBq;
    LD_BG(bgA, 0)
    SBq;
    WR_AREG(0)
    SBq;
    WLGq(0);        // ds_writes published
    BARq;

#define HALF_B(u, BO, BN, BGC, BGN)                                           \
    {                                                                         \
        /* P1: read F(mi0-1),G(mi2-3); load next A tile to regs */            \
        RD_A2(F, BO, 0)                                                       \
        SBq;                                                                  \
        RD_A2(G, BO, 2)                                                       \
        SBq;                                                                  \
        LD_AREG((u) + 1)                                                      \
        SBq;                                                                  \
        BARq;                                                                 \
        WLGq(4);                                                              \
        SBq;                                                                  \
        MFMA_T(0, F, BGC)                                                     \
        SBq;                                                                  \
        BARq;                                                                 \
        /* P2: read F'(mi4-5); load next-tile B frags */                      \
        RD_A2(F, BO, 4)                                                       \
        SBq;                                                                  \
        LD_BG(BGN, (u) + 1)                                                   \
        SBq;                                                                  \
        BARq;                                                                 \
        WLGq(4);                                                              \
        SBq;                                                                  \
        MFMA_T(2, G, BGC)                                                     \
        SBq;                                                                  \
        BARq;                                                                 \
        /* P3: read G'(mi6-7) */                                              \
        RD_A2(G, BO, 6)                                                       \
        SBq;                                                                  \
        BARq;                                                                 \
        WLGq(4);                                                              \
        SBq;                                                                  \
        MFMA_T(4, F, BGC)                                                     \
        SBq;                                                                  \
        BARq;                                                                 \
        /* P4: ds_write next A tile; drain ALL lgkm; last MFMA; publish */    \
        WR_AREG(BN)                                                           \
        SBq;                                                                  \
        WLGq(0);                                                              \
        SBq;                                                                  \
        MFMA_T(6, G, BGC)                                                     \
        SBq;                                                                  \
        BARq;                                                                 \
    }

    for (int it = 0; it < NIT; ++it) {
        const int t = 2 * it;
        HALF_B(t, 0, 32768, bgA, bgB)
        HALF_B(t + 1, 32768, 0, bgB, bgA)
    }

#undef HALF_B
#undef MFMA_T
#undef LD_BG
#undef RD_A2
#undef WR_AREG
#undef LD_AREG
#undef WLGq
#undef BARq
#undef SBq
#undef LDRB

    // epilogue: C/D layout col = lane&15, row = quad*4 + reg
    const int rbase = row0 + wm * 128 + quad * 4;
    const int cbase = col0 + wn * (NI * 16) + lm;
    if (BF16_OUT) {
        u16* C = (u16*)Cout;
#pragma unroll
        for (int mi = 0; mi < 8; mi++)
#pragma unroll
            for (int r = 0; r < 4; r++) {
                size_t ro = (size_t)(rbase + mi * 16 + r) * N;
#pragma unroll
                for (int ni = 0; ni < NI; ni++)
                    C[ro + cbase + ni * 16] = f2bf(acc[mi][ni][r]);
            }
    } else {
        float* C = (float*)Cout;
#pragma unroll
        for (int mi = 0; mi < 8; mi++)
#pragma unroll
            for (int r = 0; r < 4; r++) {
                size_t ro = (size_t)(rbase + mi * 16 + r) * N;
#pragma unroll
                for (int ni = 0; ni < NI; ni++)
                    C[ro + cbase + ni * 16] = acc[mi][ni][r];
            }
    }
}

// ---------------------------------------------------------------------------
// LDS-B variant (out-proj, NI=4): the round-3 proven kernel, unchanged.
// Pure global_load_lds vm-queue (homogeneous -> in-order counted vmcnt is
// sound). 256x256x(BK=64) 8-phase, counted lgkm waits + cross-phase prefetch.
// ---------------------------------------------------------------------------
template <int NI, bool BF16_OUT>
__global__ __launch_bounds__(512, 2)
void gemm_bt8(const u16* __restrict__ A, const u16* __restrict__ B,
              void* __restrict__ Cout, int N, int K) {
    constexpr int SZ = 32768 + NI * 8192;       // bytes per LDS buffer
    __shared__ __align__(16) char ldsc[2 * SZ];

    const int tid  = threadIdx.x;
    const int w    = tid >> 6;
    const int lane = tid & 63;
    const int row0 = blockIdx.x * 256;
    const int col0 = blockIdx.y * (NI * 64);
    const int wm = w >> 2, wn = w & 3;
    const int lm = lane & 15, quad = lane >> 4;

    const int NT  = K / 64;     // K-tiles
    const int NIT = K / 128;    // main-loop iterations (2 tiles each)
    const int K64 = K * 64;

    const int sr  = lane >> 3;
    const int stC = ((lane & 7) ^ sr) * 8;
    const u16* pA = A + (size_t)(row0 + w * 8 + sr) * K + stC;
    const u16* pB = B + (size_t)(col0 + w * 8 + sr) * K + stC;
    const int stagoff = w * 1024;

    const int cx0   = (quad ^ (lm & 7)) * 16;
    const int cx1   = cx0 ^ 64;
    const int aBase = (wm * 128 + lm) * 128;
    const int bBase = 32768 + (wn * (NI * 16) + lm) * 128;

    f32x4 acc[8][NI];
#pragma unroll
    for (int i = 0; i < 8; i++)
#pragma unroll
        for (int j = 0; j < NI; j++) acc[i][j] = (f32x4){0.f, 0.f, 0.f, 0.f};

    auto stage = [&](const u16* base, int v, int unit, int regionOff) {
        int kb = (v < NT ? v : NT - 1) * 64;    // clamp: tail re-stage (dup data)
        async_cp16(base + (size_t)unit * K64 + kb,
                   ldsc + (v & 1) * SZ + regionOff + unit * 8192 + stagoff);
    };
#define ST_A(v, u) stage(pA, (v), (u), 0)
#define ST_B(v, u) stage(pB, (v), (u), 32768)

#define LDR(off) (*(const bf16x8*)(ldsc + (off)))
#define SB __builtin_amdgcn_sched_barrier(0)
#define BAR __builtin_amdgcn_s_barrier()
#define WLG(n) asm volatile("s_waitcnt lgkmcnt(" #n ")" ::: "memory")

#define RD_AF(DST, BASEOFF, MIBASE)                                           \
    _Pragma("unroll")                                                         \
    for (int j = 0; j < 2; j++) {                                             \
        DST[j][0] = LDR((BASEOFF) + aBase + ((MIBASE) + j) * 2048 + cx0);     \
        DST[j][1] = LDR((BASEOFF) + aBase + ((MIBASE) + j) * 2048 + cx1);     \
    }
#define RD_BG(DST, BASEOFF)                                                   \
    _Pragma("unroll")                                                         \
    for (int ni = 0; ni < NI; ni++) {                                         \
        DST[ni][0] = LDR((BASEOFF) + bBase + ni * 2048 + cx0);                \
        DST[ni][1] = LDR((BASEOFF) + bBase + ni * 2048 + cx1);                \
    }
#define MFMA_TAIL(MI0, AF, BG)                                                \
    __builtin_amdgcn_s_setprio(1);                                            \
    _Pragma("unroll")                                                         \
    for (int s = 0; s < 2; s++)                                               \
        _Pragma("unroll")                                                     \
        for (int j = 0; j < 2; j++)                                           \
            _Pragma("unroll")                                                 \
            for (int ni = 0; ni < NI; ni++)                                   \
                acc[(MI0) + j][ni] = __builtin_amdgcn_mfma_f32_16x16x32_bf16( \
                    AF[j][s], BG[ni][s], acc[(MI0) + j][ni], 0, 0, 0);        \
    __builtin_amdgcn_s_setprio(0);

    bf16x8 bgA[NI][2], bgB[NI][2], F[2][2], G[2][2];

    // prologue: t0 complete (4+NI units) + t1 {B*, A0} (NI+1 units)
#pragma unroll
    for (int u = 0; u < 4; u++) ST_A(0, u);
#pragma unroll
    for (int u = 0; u < NI; u++) ST_B(0, u);
#pragma unroll
    for (int u = 0; u < NI; u++) ST_B(1, u);
    ST_A(1, 0);
    if constexpr (NI == 3) asm volatile("s_waitcnt vmcnt(4)" ::: "memory");
    else                   asm volatile("s_waitcnt vmcnt(5)" ::: "memory");
    SB;
    if constexpr (NI == 3) { RD_BG(bgA, 0) }
    RD_AF(F, 0, 0)
    SB;
    BAR;

#define HALF_ITER(u, BO, BN, BGC, BGN)                                        \
    {                                                                         \
        /* P1 */                                                              \
        if constexpr (NI == 4) { RD_BG(BGC, BO) }                             \
        SB;                                                                   \
        RD_AF(G, BO, 2)                                                       \
        SB;                                                                   \
        ST_A((u) + 1, 1); ST_A((u) + 1, 2); ST_A((u) + 1, 3);                 \
        SB;                                                                   \
        BAR;                                                                  \
        WLG(4);                                                               \
        SB;                                                                   \
        MFMA_TAIL(0, F, BGC)                                                  \
        SB;                                                                   \
        BAR;                                                                  \
        /* P2 */                                                              \
        RD_AF(F, BO, 4)                                                       \
        SB;                                                                   \
        ST_B((u) + 2, 0); ST_B((u) + 2, 1);                                   \
        SB;                                                                   \
        BAR;                                                                  \
        WLG(4);                                                               \
        SB;                                                                   \
        MFMA_TAIL(2, G, BGC)                                                  \
        SB;                                                                   \
        BAR;                                                                  \
        /* P3 */                                                              \
        RD_AF(G, BO, 6)                                                       \
        SB;                                                                   \
        ST_B((u) + 2, 2);                                                     \
        if constexpr (NI == 4) { ST_B((u) + 2, 3); }                          \
        ST_A((u) + 2, 0);                                                     \
        SB;                                                                   \
        BAR;                                                                  \
        WLG(4);                                                               \
        SB;                                                                   \
        MFMA_TAIL(4, F, BGC)                                                  \
        SB;                                                                   \
        BAR;                                                                  \
        /* P4 (no pre-stages; single barrier at end) */                       \
        WLG(0);                                                               \
        SB;                                                                   \
        MFMA_TAIL(6, G, BGC)                                                  \
        SB;                                                                   \
        if constexpr (NI == 3) asm volatile("s_waitcnt vmcnt(4)" ::: "memory");\
        else                   asm volatile("s_waitcnt vmcnt(5)" ::: "memory");\
        SB;                                                                   \
        if constexpr (NI == 3) { RD_BG(BGN, BN) }                             \
        RD_AF(F, BN, 0)                                                       \
        SB;                                                                   \
        BAR;                                                                  \
    }

    for (int it = 0; it < NIT; ++it) {
        const int t = 2 * it;
        HALF_ITER(t, 0, SZ, bgA, bgB)
        HALF_ITER(t + 1, SZ, 0, bgB, bgA)
    }

#undef HALF_ITER
#undef MFMA_TAIL
#undef RD_BG
#undef RD_AF
#undef WLG
#undef BAR
#undef SB
#undef LDR
#undef ST_A
#undef ST_B

    // epilogue: C/D layout col = lane&15, row = quad*4 + reg
    const int rbase = row0 + wm * 128 + quad * 4;
    const int cbase = col0 + wn * (NI * 16) + lm;
    if (BF16_OUT) {
        u16* C = (u16*)Cout;
#pragma unroll
        for (int mi = 0; mi < 8; mi++)
#pragma unroll
            for (int r = 0; r < 4; r++) {
                size_t ro = (size_t)(rbase + mi * 16 + r) * N;
#pragma unroll
                for (int ni = 0; ni < NI; ni++)
                    C[ro + cbase + ni * 16] = f2bf(acc[mi][ni][r]);
            }
    } else {
        float* C = (float*)Cout;
#pragma unroll
        for (int mi = 0; mi < 8; mi++)
#pragma unroll
            for (int r = 0; r < 4; r++) {
                size_t ro = (size_t)(rbase + mi * 16 + r) * N;
#pragma unroll
                for (int ni = 0; ni < NI; ni++)
                    C[ro + cbase + ni * 16] = acc[mi][ni][r];
            }
    }
}

// ---------------------------------------------------------------------------
// Per-token attention. qkv row: [q(2048) | k(512) | v(512)] bf16.
// RoPE dropped (same-position q/k rotation cancels in the dot);
// 4x head repeat collapsed (softmax over 8 distinct kv-heads).
// ---------------------------------------------------------------------------
__global__ __launch_bounds__(256)
void attn_tok(const u16* __restrict__ qkv, u16* __restrict__ out) {
    __shared__ float kvf[1024];   // k (512 floats) then v (512 floats)
    const int tok = blockIdx.x;
    const int t = threadIdx.x;
    const u16* qrow = qkv + (size_t)tok * 3072;

    {   // stage k|v (contiguous 1024 bf16) into LDS as fp32
        uint2 w = *(const uint2*)(qrow + 2048 + t * 4);
        kvf[t * 4 + 0] = bf2f((u16)(w.x & 0xffff));
        kvf[t * 4 + 1] = bf2f((u16)(w.x >> 16));
        kvf[t * 4 + 2] = bf2f((u16)(w.y & 0xffff));
        kvf[t * 4 + 3] = bf2f((u16)(w.y >> 16));
    }
    __syncthreads();

    const int h = t >> 3, j = t & 7;
    float qf[8];
    {
        uint4 w = *(const uint4*)(qrow + h * 64 + j * 8);
        unsigned ws4[4] = {w.x, w.y, w.z, w.w};
#pragma unroll
        for (int i = 0; i < 4; i++) {
            qf[2 * i]     = bf2f((u16)(ws4[i] & 0xffff));
            qf[2 * i + 1] = bf2f((u16)(ws4[i] >> 16));
        }
    }

    float s[8];
#pragma unroll
    for (int g = 0; g < 8; g++) {
        const float* kk = kvf + g * 64 + j * 8;
        float a = 0.f;
#pragma unroll
        for (int d = 0; d < 8; d++) a += qf[d] * kk[d];
        s[g] = a;
    }
#pragma unroll
    for (int g = 0; g < 8; g++) {   // reduce across the head's 8 lanes
        s[g] += __shfl_xor(s[g], 1);
        s[g] += __shfl_xor(s[g], 2);
        s[g] += __shfl_xor(s[g], 4);
    }
    float m = -1e30f;
#pragma unroll
    for (int g = 0; g < 8; g++) { s[g] *= 0.125f; m = fmaxf(m, s[g]); }
    float p[8], l = 0.f;
#pragma unroll
    for (int g = 0; g < 8; g++) { p[g] = __expf(s[g] - m); l += p[g]; }
    float rl = 1.f / l;

    float o[8] = {0, 0, 0, 0, 0, 0, 0, 0};
#pragma unroll
    for (int g = 0; g < 8; g++) {
        float w = p[g] * rl;
        const float* vv = kvf + 512 + g * 64 + j * 8;
#pragma unroll
        for (int d = 0; d < 8; d++) o[d] += w * vv[d];
    }

    unsigned po[4];
#pragma unroll
    for (int i = 0; i < 4; i++)
        po[i] = (unsigned)f2bf(o[2 * i]) | ((unsigned)f2bf(o[2 * i + 1]) << 16);
    uint4 wo_; wo_.x = po[0]; wo_.y = po[1]; wo_.z = po[2]; wo_.w = po[3];
    *(uint4*)(out + (size_t)tok * 2048 + h * 64 + j * 8) = wo_;
}

// ---------------------------------------------------------------------------
// B=4, S=2048, DIM=2048, H=32, KVH=8, HD=64. Tokens M = 8192.
// Workspace (u16 elems): x_bf/attn (aliased) 16777216 | wqkv 6291456
//                        | wo_bf 4194304 | qkv 25165824   (104.9 MB)
// ---------------------------------------------------------------------------
extern "C" void kernel_launch(void* const* d_in, const int* in_sizes, int n_in,
                              void* d_out, int out_size, void* d_ws, size_t ws_size,
                              hipStream_t stream) {
    const float* x  = (const float*)d_in[0];
    const float* wq = (const float*)d_in[1];
    const float* wk = (const float*)d_in[2];
    const float* wv = (const float*)d_in[3];
    const float* wo = (const float*)d_in[4];
    // d_in[5]/d_in[6] (freqs_cos/sin) unused: RoPE cancels in same-position dots.

    u16* x_bf  = (u16*)d_ws;
    u16* wqkv  = x_bf  + 16777216;
    u16* wo_bf = wqkv  + 6291456;
    u16* qkv   = wo_bf + 4194304;    // 8192 x 3072
    u16* attn  = x_bf;               // alias: x_bf dead after QKV GEMM

    conv_all<<<18432, dim3(256), 0, stream>>>(x, wq, wk, wv, wo, x_bf, wqkv, wo_bf);

    // fused QKV projection: [8192 x 2048] x [3072 x 2048]^T -> [8192 x 3072]
    // reg-staged-A + direct-B variant; 32x16 = 512 blocks = 2 exact rounds
    gemm_breg<3, true><<<dim3(32, 16), dim3(512), 0, stream>>>(x_bf, wqkv, qkv,
                                                               3072, 2048);

    attn_tok<<<8192, dim3(256), 0, stream>>>(qkv, attn);

    // output projection: [8192 x 2048] x [2048 x 2048]^T -> fp32 d_out
    // LDS-B proven path; 256x256 tile -> 32x8 = 256 blocks = 1 exact round
    gemm_bt8<4, false><<<dim3(32, 8), dim3(512), 0, stream>>>(attn, wo_bf,
                                                              (float*)d_out,
                                                              2048, 2048);
}

// Round 7
// 320.513 us; speedup vs baseline: 1.1297x; 1.1297x over previous
//
#include <hip/hip_runtime.h>

typedef unsigned short u16;
typedef __bf16 bf16x8 __attribute__((ext_vector_type(8)));
typedef float f32x4 __attribute__((ext_vector_type(4)));

#define AS1 __attribute__((address_space(1)))
#define AS3 __attribute__((address_space(3)))

__device__ inline u16 f2bf(float f) {
    union { float f; unsigned u; } c; c.f = f;
    unsigned u = c.u;
    u += 0x7fffu + ((u >> 16) & 1u);   // round-to-nearest-even
    return (u16)(u >> 16);
}
__device__ inline float bf2f(u16 b) {
    union { unsigned u; float f; } c; c.u = ((unsigned)b) << 16;
    return c.f;
}

__device__ inline void async_cp16(const void* g, void* l) {
    __builtin_amdgcn_global_load_lds((const AS1 void*)g, (AS3 void*)l, 16, 0, 0);
}

// ---------------------------------------------------------------------------
// Fused input conversions in ONE launch:
//   blocks [0, 8192):      x fp32 -> bf16, 8 elems/thread (16777216 elems)
//   blocks [8192, 18432):  wq|wk|wv -> wqkv, wo -> wo_bf, 4 elems/thread
// ---------------------------------------------------------------------------
__global__ __launch_bounds__(256)
void conv_all(const float* __restrict__ x,
              const float* __restrict__ wq, const float* __restrict__ wk,
              const float* __restrict__ wv, const float* __restrict__ wo,
              u16* __restrict__ x_bf, u16* __restrict__ wqkv,
              u16* __restrict__ wo_bf) {
    int b = blockIdx.x;
    if (b < 8192) {
        int i = (b * 256 + threadIdx.x) * 8;
        float4 f0 = *(const float4*)(x + i);
        float4 f1 = *(const float4*)(x + i + 4);
        union { u16 h[8]; uint4 v; } o;
        o.h[0] = f2bf(f0.x); o.h[1] = f2bf(f0.y);
        o.h[2] = f2bf(f0.z); o.h[3] = f2bf(f0.w);
        o.h[4] = f2bf(f1.x); o.h[5] = f2bf(f1.y);
        o.h[6] = f2bf(f1.z); o.h[7] = f2bf(f1.w);
        *(uint4*)(x_bf + i) = o.v;
    } else {
        int i = ((b - 8192) * 256 + threadIdx.x) * 4;
        const float* src;
        u16* dst;
        if (i < 4194304)       { src = wq + i;           dst = wqkv + i; }
        else if (i < 5242880)  { src = wk + (i-4194304); dst = wqkv + i; }
        else if (i < 6291456)  { src = wv + (i-5242880); dst = wqkv + i; }
        else                   { src = wo + (i-6291456); dst = wo_bf + (i-6291456); }
        float4 f = *(const float4*)src;
        union { u16 h[4]; uint2 v; } o;
        o.h[0] = f2bf(f.x); o.h[1] = f2bf(f.y);
        o.h[2] = f2bf(f.z); o.h[3] = f2bf(f.w);
        *(uint2*)dst = o.v;
    }
}

// ---------------------------------------------------------------------------
// 256 x (NI*64) x (BK=64) 8-phase bf16 GEMM, C = A * B^T (row-major, K contig)
// with COUNTED per-phase lgkm waits and cross-phase operand prefetch.
// (Round-3 proven kernel, restored verbatim after the round-6 breg regression
//  refuted the LDS-bandwidth theory: removing B's LDS traffic LOWERED
//  MfmaUtil 44->31% -- LDS reads were already hidden under MFMA.)
// 512 threads = 8 waves (2M x 4N), per-wave output 128 x (NI*16), acc[8][NI].
// NI=3: QKV (grid 32x16 = 512 blocks = 2 exact rounds), bg double-buffered
//       (prefetched in P4 of the previous tile). NI=4: out-proj, bg read in P1.
// Stage ledger and vmcnt discipline: see round-3 notes; homogeneous
// global_load_lds vm-queue -> counted vmcnt sound.
// Requires: M %256==0, N %(NI*64)==0, K %128==0.
// ---------------------------------------------------------------------------
template <int NI, bool BF16_OUT>
__global__ __launch_bounds__(512, 2)
void gemm_bt8(const u16* __restrict__ A, const u16* __restrict__ B,
              void* __restrict__ Cout, int N, int K) {
    constexpr int SZ = 32768 + NI * 8192;       // bytes per LDS buffer
    __shared__ __align__(16) char ldsc[2 * SZ];

    const int tid  = threadIdx.x;
    const int w    = tid >> 6;
    const int lane = tid & 63;
    const int row0 = blockIdx.x * 256;
    const int col0 = blockIdx.y * (NI * 64);
    const int wm = w >> 2, wn = w & 3;
    const int lm = lane & 15, quad = lane >> 4;

    const int NT  = K / 64;     // K-tiles
    const int NIT = K / 128;    // main-loop iterations (2 tiles each)
    const int K64 = K * 64;

    // staging: lane l covers row (8w + (l>>3)) within a 64-row unit,
    // LDS chunk position l&7 holds global chunk (l&7)^(l>>3)  (swizzle)
    const int sr  = lane >> 3;
    const int stC = ((lane & 7) ^ sr) * 8;
    const u16* pA = A + (size_t)(row0 + w * 8 + sr) * K + stC;
    const u16* pB = B + (size_t)(col0 + w * 8 + sr) * K + stC;
    const int stagoff = w * 1024;

    // fragment read bases (byte offsets); frag row&7 == lm&7 (row blocks %8==0)
    const int cx0   = (quad ^ (lm & 7)) * 16;
    const int cx1   = cx0 ^ 64;
    const int aBase = (wm * 128 + lm) * 128;
    const int bBase = 32768 + (wn * (NI * 16) + lm) * 128;

    f32x4 acc[8][NI];
#pragma unroll
    for (int i = 0; i < 8; i++)
#pragma unroll
        for (int j = 0; j < NI; j++) acc[i][j] = (f32x4){0.f, 0.f, 0.f, 0.f};

    auto stage = [&](const u16* base, int v, int unit, int regionOff) {
        int kb = (v < NT ? v : NT - 1) * 64;    // clamp: tail re-stage (dup data)
        async_cp16(base + (size_t)unit * K64 + kb,
                   ldsc + (v & 1) * SZ + regionOff + unit * 8192 + stagoff);
    };
#define ST_A(v, u) stage(pA, (v), (u), 0)
#define ST_B(v, u) stage(pB, (v), (u), 32768)

#define LDR(off) (*(const bf16x8*)(ldsc + (off)))
#define SB __builtin_amdgcn_sched_barrier(0)
#define BAR __builtin_amdgcn_s_barrier()
#define WLG(n) asm volatile("s_waitcnt lgkmcnt(" #n ")" ::: "memory")

#define RD_AF(DST, BASEOFF, MIBASE)                                           \
    _Pragma("unroll")                                                         \
    for (int j = 0; j < 2; j++) {                                             \
        DST[j][0] = LDR((BASEOFF) + aBase + ((MIBASE) + j) * 2048 + cx0);     \
        DST[j][1] = LDR((BASEOFF) + aBase + ((MIBASE) + j) * 2048 + cx1);     \
    }
#define RD_BG(DST, BASEOFF)                                                   \
    _Pragma("unroll")                                                         \
    for (int ni = 0; ni < NI; ni++) {                                         \
        DST[ni][0] = LDR((BASEOFF) + bBase + ni * 2048 + cx0);                \
        DST[ni][1] = LDR((BASEOFF) + bBase + ni * 2048 + cx1);                \
    }
#define MFMA_TAIL(MI0, AF, BG)                                                \
    __builtin_amdgcn_s_setprio(1);                                            \
    _Pragma("unroll")                                                         \
    for (int s = 0; s < 2; s++)                                               \
        _Pragma("unroll")                                                     \
        for (int j = 0; j < 2; j++)                                           \
            _Pragma("unroll")                                                 \
            for (int ni = 0; ni < NI; ni++)                                   \
                acc[(MI0) + j][ni] = __builtin_amdgcn_mfma_f32_16x16x32_bf16( \
                    AF[j][s], BG[ni][s], acc[(MI0) + j][ni], 0, 0, 0);        \
    __builtin_amdgcn_s_setprio(0);

    bf16x8 bgA[NI][2], bgB[NI][2], F[2][2], G[2][2];

    // prologue: t0 complete (4+NI units) + t1 {B*, A0} (NI+1 units)
#pragma unroll
    for (int u = 0; u < 4; u++) ST_A(0, u);
#pragma unroll
    for (int u = 0; u < NI; u++) ST_B(0, u);
#pragma unroll
    for (int u = 0; u < NI; u++) ST_B(1, u);
    ST_A(1, 0);
    if constexpr (NI == 3) asm volatile("s_waitcnt vmcnt(4)" ::: "memory");
    else                   asm volatile("s_waitcnt vmcnt(5)" ::: "memory");
    SB;
    if constexpr (NI == 3) { RD_BG(bgA, 0) }
    RD_AF(F, 0, 0)
    SB;
    BAR;

#define HALF_ITER(u, BO, BN, BGC, BGN)                                        \
    {                                                                         \
        /* P1 */                                                              \
        if constexpr (NI == 4) { RD_BG(BGC, BO) }                             \
        SB;                                                                   \
        RD_AF(G, BO, 2)                                                       \
        SB;                                                                   \
        ST_A((u) + 1, 1); ST_A((u) + 1, 2); ST_A((u) + 1, 3);                 \
        SB;                                                                   \
        BAR;                                                                  \
        WLG(4);                                                               \
        SB;                                                                   \
        MFMA_TAIL(0, F, BGC)                                                  \
        SB;                                                                   \
        BAR;                                                                  \
        /* P2 */                                                              \
        RD_AF(F, BO, 4)                                                       \
        SB;                                                                   \
        ST_B((u) + 2, 0); ST_B((u) + 2, 1);                                   \
        SB;                                                                   \
        BAR;                                                                  \
        WLG(4);                                                               \
        SB;                                                                   \
        MFMA_TAIL(2, G, BGC)                                                  \
        SB;                                                                   \
        BAR;                                                                  \
        /* P3 */                                                              \
        RD_AF(G, BO, 6)                                                       \
        SB;                                                                   \
        ST_B((u) + 2, 2);                                                     \
        if constexpr (NI == 4) { ST_B((u) + 2, 3); }                          \
        ST_A((u) + 2, 0);                                                     \
        SB;                                                                   \
        BAR;                                                                  \
        WLG(4);                                                               \
        SB;                                                                   \
        MFMA_TAIL(4, F, BGC)                                                  \
        SB;                                                                   \
        BAR;                                                                  \
        /* P4 (no pre-stages; single barrier at end) */                       \
        WLG(0);                                                               \
        SB;                                                                   \
        MFMA_TAIL(6, G, BGC)                                                  \
        SB;                                                                   \
        if constexpr (NI == 3) asm volatile("s_waitcnt vmcnt(4)" ::: "memory");\
        else                   asm volatile("s_waitcnt vmcnt(5)" ::: "memory");\
        SB;                                                                   \
        if constexpr (NI == 3) { RD_BG(BGN, BN) }                             \
        RD_AF(F, BN, 0)                                                       \
        SB;                                                                   \
        BAR;                                                                  \
    }

    for (int it = 0; it < NIT; ++it) {
        const int t = 2 * it;
        HALF_ITER(t, 0, SZ, bgA, bgB)
        HALF_ITER(t + 1, SZ, 0, bgB, bgA)
    }

#undef HALF_ITER
#undef MFMA_TAIL
#undef RD_BG
#undef RD_AF
#undef WLG
#undef BAR
#undef SB
#undef LDR
#undef ST_A
#undef ST_B

    // epilogue: C/D layout col = lane&15, row = quad*4 + reg
    const int rbase = row0 + wm * 128 + quad * 4;
    const int cbase = col0 + wn * (NI * 16) + lm;
    if (BF16_OUT) {
        u16* C = (u16*)Cout;
#pragma unroll
        for (int mi = 0; mi < 8; mi++)
#pragma unroll
            for (int r = 0; r < 4; r++) {
                size_t ro = (size_t)(rbase + mi * 16 + r) * N;
#pragma unroll
                for (int ni = 0; ni < NI; ni++)
                    C[ro + cbase + ni * 16] = f2bf(acc[mi][ni][r]);
            }
    } else {
        float* C = (float*)Cout;
#pragma unroll
        for (int mi = 0; mi < 8; mi++)
#pragma unroll
            for (int r = 0; r < 4; r++) {
                size_t ro = (size_t)(rbase + mi * 16 + r) * N;
#pragma unroll
                for (int ni = 0; ni < NI; ni++)
                    C[ro + cbase + ni * 16] = acc[mi][ni][r];
            }
    }
}

// ---------------------------------------------------------------------------
// Per-token attention. qkv row: [q(2048) | k(512) | v(512)] bf16.
// RoPE dropped (same-position q/k rotation cancels in the dot);
// 4x head repeat collapsed (softmax over 8 distinct kv-heads).
// Round 7: k/v LDS reads vectorized to float4 (128 scalar ds_read_b32 per
// thread -> 32 ds_read_b128; the kernel is LDS-issue-bound, not HBM-bound).
// Accumulation order identical to the scalar version (bit-identical output).
// ---------------------------------------------------------------------------
__global__ __launch_bounds__(256)
void attn_tok(const u16* __restrict__ qkv, u16* __restrict__ out) {
    __shared__ float kvf[1024];   // k (512 floats) then v (512 floats)
    const int tok = blockIdx.x;
    const int t = threadIdx.x;
    const u16* qrow = qkv + (size_t)tok * 3072;

    {   // stage k|v (contiguous 1024 bf16) into LDS as fp32
        uint2 w = *(const uint2*)(qrow + 2048 + t * 4);
        kvf[t * 4 + 0] = bf2f((u16)(w.x & 0xffff));
        kvf[t * 4 + 1] = bf2f((u16)(w.x >> 16));
        kvf[t * 4 + 2] = bf2f((u16)(w.y & 0xffff));
        kvf[t * 4 + 3] = bf2f((u16)(w.y >> 16));
    }
    __syncthreads();

    const int h = t >> 3, j = t & 7;
    float qf[8];
    {
        uint4 w = *(const uint4*)(qrow + h * 64 + j * 8);
        unsigned ws4[4] = {w.x, w.y, w.z, w.w};
#pragma unroll
        for (int i = 0; i < 4; i++) {
            qf[2 * i]     = bf2f((u16)(ws4[i] & 0xffff));
            qf[2 * i + 1] = bf2f((u16)(ws4[i] >> 16));
        }
    }

    float s[8];
#pragma unroll
    for (int g = 0; g < 8; g++) {
        const float4* kk = (const float4*)(kvf + g * 64 + j * 8);  // 32B-aligned
        float4 k0 = kk[0], k1 = kk[1];
        s[g] = qf[0] * k0.x + qf[1] * k0.y + qf[2] * k0.z + qf[3] * k0.w
             + qf[4] * k1.x + qf[5] * k1.y + qf[6] * k1.z + qf[7] * k1.w;
    }
#pragma unroll
    for (int g = 0; g < 8; g++) {   // reduce across the head's 8 lanes
        s[g] += __shfl_xor(s[g], 1);
        s[g] += __shfl_xor(s[g], 2);
        s[g] += __shfl_xor(s[g], 4);
    }
    float m = -1e30f;
#pragma unroll
    for (int g = 0; g < 8; g++) { s[g] *= 0.125f; m = fmaxf(m, s[g]); }
    float p[8], l = 0.f;
#pragma unroll
    for (int g = 0; g < 8; g++) { p[g] = __expf(s[g] - m); l += p[g]; }
    float rl = 1.f / l;

    float o[8] = {0, 0, 0, 0, 0, 0, 0, 0};
#pragma unroll
    for (int g = 0; g < 8; g++) {
        float wgt = p[g] * rl;
        const float4* vv = (const float4*)(kvf + 512 + g * 64 + j * 8);
        float4 v0 = vv[0], v1 = vv[1];
        o[0] += wgt * v0.x; o[1] += wgt * v0.y;
        o[2] += wgt * v0.z; o[3] += wgt * v0.w;
        o[4] += wgt * v1.x; o[5] += wgt * v1.y;
        o[6] += wgt * v1.z; o[7] += wgt * v1.w;
    }

    unsigned po[4];
#pragma unroll
    for (int i = 0; i < 4; i++)
        po[i] = (unsigned)f2bf(o[2 * i]) | ((unsigned)f2bf(o[2 * i + 1]) << 16);
    uint4 wo_; wo_.x = po[0]; wo_.y = po[1]; wo_.z = po[2]; wo_.w = po[3];
    *(uint4*)(out + (size_t)tok * 2048 + h * 64 + j * 8) = wo_;
}

// ---------------------------------------------------------------------------
// B=4, S=2048, DIM=2048, H=32, KVH=8, HD=64. Tokens M = 8192.
// Workspace (u16 elems): x_bf/attn (aliased) 16777216 | wqkv 6291456
//                        | wo_bf 4194304 | qkv 25165824   (104.9 MB)
// ---------------------------------------------------------------------------
extern "C" void kernel_launch(void* const* d_in, const int* in_sizes, int n_in,
                              void* d_out, int out_size, void* d_ws, size_t ws_size,
                              hipStream_t stream) {
    const float* x  = (const float*)d_in[0];
    const float* wq = (const float*)d_in[1];
    const float* wk = (const float*)d_in[2];
    const float* wv = (const float*)d_in[3];
    const float* wo = (const float*)d_in[4];
    // d_in[5]/d_in[6] (freqs_cos/sin) unused: RoPE cancels in same-position dots.

    u16* x_bf  = (u16*)d_ws;
    u16* wqkv  = x_bf  + 16777216;
    u16* wo_bf = wqkv  + 6291456;
    u16* qkv   = wo_bf + 4194304;    // 8192 x 3072
    u16* attn  = x_bf;               // alias: x_bf dead after QKV GEMM

    conv_all<<<18432, dim3(256), 0, stream>>>(x, wq, wk, wv, wo, x_bf, wqkv, wo_bf);

    // fused QKV projection: [8192 x 2048] x [3072 x 2048]^T -> [8192 x 3072]
    // 256x192 tile -> 32x16 = 512 blocks = 2 exact machine rounds
    gemm_bt8<3, true><<<dim3(32, 16), dim3(512), 0, stream>>>(x_bf, wqkv, qkv,
                                                              3072, 2048);

    attn_tok<<<8192, dim3(256), 0, stream>>>(qkv, attn);

    // output projection: [8192 x 2048] x [2048 x 2048]^T -> fp32 d_out
    // 256x256 tile -> 32x8 = 256 blocks = 1 exact machine round
    gemm_bt8<4, false><<<dim3(32, 8), dim3(512), 0, stream>>>(attn, wo_bf,
                                                              (float*)d_out,
                                                              2048, 2048);
}